// Round 1
// baseline (342.747 us; speedup 1.0000x reference)
//
#include <hip/hip_runtime.h>

#define T 4
#define D 1024
#define NN 256
#define K 64
#define V 32000
// derived
#define VK (V*K)          // 2048000
#define TD (T*D)          // 4096

__device__ __forceinline__ float jexp(float x) {
    // jax_exp: clip(exp(clip(x,-700,700)), 1e-6)
    x = fminf(fmaxf(x, -700.0f), 700.0f);
    return fmaxf(expf(x), 1e-6f);
}

// ---------------- eta SGLD update: one wave per (t,d) row ----------------
__global__ void eta_kernel(const float* __restrict__ eta,
                           const float* __restrict__ alpha,
                           const float* __restrict__ CDK,
                           const float* __restrict__ noise_eta,
                           float* __restrict__ eta_new)
{
    int wave = threadIdx.x >> 6;
    int lane = threadIdx.x & 63;
    int r = blockIdx.x * 4 + wave;          // (t*D + d), r < TD
    int t = r / D;
    float x = eta[r * K + lane];
    // wave-wide max (width 64)
    float m = x;
    #pragma unroll
    for (int off = 32; off >= 1; off >>= 1)
        m = fmaxf(m, __shfl_xor(m, off, 64));
    float e = expf(x - m);
    float s = e;
    #pragma unroll
    for (int off = 32; off >= 1; off >>= 1)
        s += __shfl_xor(s, off, 64);
    float sm = e / s;
    float grad  = CDK[r * K + lane] - (float)NN * sm;
    float prior = alpha[t * K + lane] - x;          // ETA_VAR = 1
    eta_new[r * K + lane] = x + 0.005f * (grad + prior) + noise_eta[r] * 0.01f;
}

// ---------------- per-(t,k) sum of exp(phi[t,:,k]) over V ----------------
// grid = T*125 blocks; each block covers 256 consecutive v-rows of one t.
__global__ void phi_colsum_kernel(const float* __restrict__ phi,
                                  float* __restrict__ S)   // S[T*K], pre-zeroed
{
    int blk = blockIdx.x;
    int t = blk / 125;
    int vbase = (blk % 125) * 256;
    int k = threadIdx.x & 63;
    int r = threadIdx.x >> 6;               // 0..3
    const float* base = phi + (size_t)t * VK;
    float s = 0.0f;
    #pragma unroll 4
    for (int it = 0; it < 64; ++it) {
        int v = vbase + it * 4 + r;
        s += expf(base[v * K + k]);         // coalesced: tid-consecutive addrs
    }
    __shared__ float sm[256];
    sm[threadIdx.x] = s;
    __syncthreads();
    if (threadIdx.x < 64) {
        float tot = sm[threadIdx.x] + sm[threadIdx.x + 64] +
                    sm[threadIdx.x + 128] + sm[threadIdx.x + 192];
        atomicAdd(&S[t * K + k], tot);
    }
}

// ---------------- MH resampling + counter scatters ----------------
// one block per (t,d) document, 256 threads = N tokens
__global__ void mh_kernel(const int* __restrict__ W, const int* __restrict__ Z,
                          const int* __restrict__ pwi, const int* __restrict__ ptop,
                          const float* __restrict__ u, const float* __restrict__ phi,
                          const float* __restrict__ CDK,
                          const float* __restrict__ eta_new,
                          float* __restrict__ CDK_new, float* __restrict__ CWK_new,
                          float* __restrict__ CK_new, float* __restrict__ z_out)
{
    int r = blockIdx.x;             // t*D + d
    int t = r / D;
    int n = threadIdx.x;

    __shared__ int   zsh[NN];
    __shared__ float esh[K];
    __shared__ int   hist[K];

    zsh[n] = Z[r * NN + n];
    if (n < K) { esh[n] = eta_new[r * K + n]; hist[n] = 0; }
    __syncthreads();

    int w     = W[r * NN + n];
    int pre   = zsh[n];
    int prop1 = zsh[pwi[r * NN + n]];

    const float* prow = phi + ((size_t)t * V + w) * K;
    float a1 = jexp(prow[prop1]) / jexp(prow[pre]);
    float u0 = u[((size_t)r * NN + n) * 2 + 0];
    int k1 = (u0 < a1) ? prop1 : pre;

    int pt = ptop[r * NN + n];
    float a2 = jexp(esh[pt]) / jexp(esh[k1]);
    float u1 = u[((size_t)r * NN + n) * 2 + 1];
    int z = (u1 < a2) ? pt : k1;

    z_out[r * NN + n] = (float)z;

    atomicAdd(&hist[z], 1);
    atomicAdd(&hist[pre], -1);
    if (z != pre) {   // +1 then -1 at same slot is a no-op (counts < 2^24)
        atomicAdd(&CWK_new[((size_t)t * V + w) * K + z],   1.0f);
        atomicAdd(&CWK_new[((size_t)t * V + w) * K + pre], -1.0f);
    }
    __syncthreads();

    if (n < K) {
        int h = hist[n];
        CDK_new[r * K + n] = CDK[r * K + n] + (float)h;   // block owns this row
        if (h != 0) atomicAdd(&CK_new[t * K + n], (float)h);
    }
}

// ---------------- phi SGLD update, all 4 time steps in registers ----------------
__global__ void phi_update_kernel(const float* __restrict__ phi,
                                  const float* __restrict__ CWKn,
                                  const float* __restrict__ CKn,
                                  const float* __restrict__ S,
                                  const float* __restrict__ noise_phi,
                                  float* __restrict__ phi_new)
{
    int idx = blockIdx.x * 256 + threadIdx.x;   // flat (v,k), < VK
    int k = idx & 63;
    const float eps = 0.01f;
    const float half_eps = 0.005f;
    const float sig = 1.0f / 1.01f;             // phi_sigma / PHI_VAR

    float p0 = phi[idx];
    float p1 = phi[idx + VK];
    float p2 = phi[idx + 2 * VK];
    float p3 = phi[idx + 3 * VK];

    float g0 = CWKn[idx]          - CKn[k]          * (expf(p0) / S[k]);
    float g1 = CWKn[idx + VK]     - CKn[K + k]      * (expf(p1) / S[K + k]);
    float g2 = CWKn[idx + 2 * VK] - CKn[2 * K + k]  * (expf(p2) / S[2 * K + k]);
    float g3 = CWKn[idx + 3 * VK] - CKn[3 * K + k]  * (expf(p3) / S[3 * K + k]);

    float r0 = p0 + half_eps * (g0 + 2.0f * p1 * sig - 2.0f * p0) + noise_phi[0] * eps;
    float r1 = p1 + half_eps * (g1 + p2 + r0 - 2.0f * p1)         + noise_phi[1] * eps;
    float r2 = p2 + half_eps * (g2 + p3 + r1 - 2.0f * p2)         + noise_phi[2] * eps;
    float r3 = p3 + half_eps * (g3 + r2 - p3)                      + noise_phi[3] * eps;

    phi_new[idx]          = r0;
    phi_new[idx + VK]     = r1;
    phi_new[idx + 2 * VK] = r2;
    phi_new[idx + 3 * VK] = r3;
}

extern "C" void kernel_launch(void* const* d_in, const int* in_sizes, int n_in,
                              void* d_out, int out_size, void* d_ws, size_t ws_size,
                              hipStream_t stream)
{
    const int*   W         = (const int*)  d_in[0];
    const int*   Z         = (const int*)  d_in[1];
    const int*   pwi       = (const int*)  d_in[2];
    const int*   ptop      = (const int*)  d_in[3];
    const float* u_mh      = (const float*)d_in[4];
    const float* noise_eta = (const float*)d_in[5];
    const float* noise_phi = (const float*)d_in[6];
    const float* alpha     = (const float*)d_in[7];
    const float* phi       = (const float*)d_in[8];
    const float* eta       = (const float*)d_in[9];
    const float* CDK       = (const float*)d_in[10];
    const float* CWK       = (const float*)d_in[11];
    const float* CK        = (const float*)d_in[12];

    float* out     = (float*)d_out;
    float* eta_new = out;                               // T*D*K   = 262144
    float* phi_new = out + 262144;                      // T*V*K   = 8192000
    float* CDK_new = out + 8454144;                     // T*D*K   = 262144
    float* CWK_new = out + 8716288;                     // T*V*K   = 8192000
    float* CK_new  = out + 16908288;                    // T*K     = 256
    float* z_out   = out + 16908544;                    // T*D*N   = 1048576

    float* S = (float*)d_ws;                            // T*K softmax denominators

    hipMemsetAsync(S, 0, T * K * sizeof(float), stream);
    hipMemcpyAsync(CWK_new, CWK, (size_t)T * VK * sizeof(float),
                   hipMemcpyDeviceToDevice, stream);
    hipMemcpyAsync(CK_new, CK, T * K * sizeof(float),
                   hipMemcpyDeviceToDevice, stream);

    eta_kernel<<<TD / 4, 256, 0, stream>>>(eta, alpha, CDK, noise_eta, eta_new);
    phi_colsum_kernel<<<T * 125, 256, 0, stream>>>(phi, S);
    mh_kernel<<<TD, 256, 0, stream>>>(W, Z, pwi, ptop, u_mh, phi, CDK,
                                      eta_new, CDK_new, CWK_new, CK_new, z_out);
    phi_update_kernel<<<VK / 256, 256, 0, stream>>>(phi, CWK_new, CK_new, S,
                                                    noise_phi, phi_new);
}